// Round 8
// baseline (1118.240 us; speedup 1.0000x reference)
//
#include <hip/hip_runtime.h>
#include <math.h>

static constexpr int NB = 2, NN = 256, HH = 256, DD = 64, LL = 6;
static constexpr int RN = NB * NN * HH;  // 131072

typedef __attribute__((ext_vector_type(8))) short bf16x8;
typedef __attribute__((ext_vector_type(4))) float f32x4;
typedef __attribute__((ext_vector_type(4))) float float4v;
typedef __attribute__((ext_vector_type(4))) unsigned int u32x4;

// fast silu: v * rcp(1+exp(-v)) — avoids the ~12-inst IEEE div lowering
__device__ __forceinline__ float fsilu(float v) {
    return v * __builtin_amdgcn_rcpf(1.0f + __expf(-v));
}
__device__ __forceinline__ unsigned short f2bf(float f) {
    union { float f; unsigned int u; } x; x.f = f;
    unsigned int r = x.u + 0x7fffu + ((x.u >> 16) & 1u);
    return (unsigned short)(r >> 16);
}
__device__ __forceinline__ float bitsf(unsigned int u) {
    union { float f; unsigned int u; } x; x.u = u; return x.f;
}
__device__ __forceinline__ unsigned int cvtpk(float lo, float hi) {
    unsigned int w;
    asm("v_cvt_pk_bf16_f32 %0, %1, %2" : "=v"(w) : "v"(lo), "v"(hi));
    return w;
}

// ---------------------------------------------------------------- convert (fragment-packed)
// elem[((ks*16 + wv8*2 + ct)*64 + lane)*8 + e] = bf16(W[k=ks*32+(lane>>4)*8+e][col=wv8*32+ct*16+(lane&15)])
__global__ void k_convert(const float* __restrict__ ew2, const float* __restrict__ cw1,
                          unsigned short* __restrict__ ew2P, unsigned short* __restrict__ cw1P) {
    int g = blockIdx.x * blockDim.x + threadIdx.x;
    if (g >= LL * 8192) return;
    int l = g >> 13;
    int r = g & 8191;
    int lane = r & 63;
    int fidx = r >> 6;
    int ks = fidx >> 4;
    int wv = (fidx >> 1) & 7;
    int ct = fidx & 1;
    int col = wv * 32 + ct * 16 + (lane & 15);
    int k0 = ks * 32 + (lane >> 4) * 8;
    #pragma unroll
    for (int e = 0; e < 8; ++e) {
        ew2P[(size_t)g * 8 + e] = f2bf(ew2[((size_t)l * HH + k0 + e) * HH + col]);
        cw1P[(size_t)g * 8 + e] = f2bf(cw1[((size_t)l * HH + k0 + e) * HH + col]);
    }
}

// ---------------------------------------------------------------- encoder (2 rows/block, broadcast staging)
__global__ __launch_bounds__(256) void k_encoder(
    const float* __restrict__ coords, const float* __restrict__ feats, const float* __restrict__ t,
    const float* __restrict__ pw1, const float* __restrict__ pb1,
    const float* __restrict__ pw2, const float* __restrict__ pb2,
    const float* __restrict__ pw3, const float* __restrict__ pb3,
    const float* __restrict__ tw1, const float* __restrict__ tb1,
    const float* __restrict__ tw2, const float* __restrict__ tb2,
    float* __restrict__ h, float* __restrict__ x) {
    __shared__ float spinT[68][2];
    __shared__ float shaT[HH][2];
    __shared__ float shbT[HH][2];
    __shared__ float ste1[HH];
    int tid = threadIdx.x;
    int base = blockIdx.x * 2;
    int b = base / NN;

    #pragma unroll
    for (int r = 0; r < 2; ++r) {
        int row = base + r;
        if (tid < 3) spinT[tid][r] = coords[row * 3 + tid];
        if (tid < DD) spinT[3 + tid][r] = feats[row * DD + tid];
    }
    float tv = t[b];
    ste1[tid] = fmaxf(tv * tw1[tid] + tb1[tid], 0.0f);
    if (tid < 6) {
        int r = tid / 3, c = tid % 3;
        x[(base + r) * 3 + c] = coords[(base + r) * 3 + c];
    }
    __syncthreads();

    float a0 = pb1[tid], a1 = a0;
    for (int c = 0; c < 67; ++c) {
        float w = pw1[c * HH + tid];
        float2 s = *(const float2*)&spinT[c][0];
        a0 += s.x * w; a1 += s.y * w;
    }
    shaT[tid][0] = fmaxf(a0, 0.f); shaT[tid][1] = fmaxf(a1, 0.f);
    __syncthreads();
    a0 = pb2[tid]; a1 = a0;
    for (int c = 0; c < HH; ++c) {
        float w = pw2[c * HH + tid];
        float2 s = *(const float2*)&shaT[c][0];
        a0 += s.x * w; a1 += s.y * w;
    }
    shbT[tid][0] = fmaxf(a0, 0.f); shbT[tid][1] = fmaxf(a1, 0.f);
    __syncthreads();
    a0 = pb3[tid]; a1 = a0;
    float te = tb2[tid];
    for (int c = 0; c < HH; ++c) {
        float w = pw3[c * HH + tid];
        float2 s = *(const float2*)&shbT[c][0];
        a0 += s.x * w; a1 += s.y * w;
        te += ste1[c] * tw2[c * HH + tid];
    }
    h[(base + 0) * HH + tid] = fmaxf(a0, 0.f) + te;
    h[(base + 1) * HH + tid] = fmaxf(a1, 0.f) + te;
}

// ---------------------------------------------------------------- LayerNorm + Ai/Aj (layer 0, 2 rows/block)
__global__ __launch_bounds__(256) void k_ln_aiaj(
    const float* __restrict__ h, const float* __restrict__ g, const float* __restrict__ bta,
    const float* __restrict__ ew1l, const float* __restrict__ eb1l,
    float* __restrict__ hn, float* __restrict__ Ai, unsigned short* __restrict__ AjB) {
    __shared__ float shnT[HH][2];
    int tid = threadIdx.x, wv = tid >> 6, lane = tid & 63;
    int base = blockIdx.x * 2;

    if (wv < 2) {
        int row = base + wv;
        float v[4];
        #pragma unroll
        for (int q = 0; q < 4; ++q) v[q] = h[row * HH + lane + 64 * q];
        float s = v[0] + v[1] + v[2] + v[3];
        #pragma unroll
        for (int m = 1; m < 64; m <<= 1) s += __shfl_xor(s, m);
        float mu = s * (1.0f / HH);
        float var = 0.f;
        #pragma unroll
        for (int q = 0; q < 4; ++q) { v[q] -= mu; var += v[q] * v[q]; }
        #pragma unroll
        for (int m = 1; m < 64; m <<= 1) var += __shfl_xor(var, m);
        float rstd = rsqrtf(var * (1.0f / HH) + 1e-5f);
        #pragma unroll
        for (int q = 0; q < 4; ++q) {
            int k = lane + 64 * q;
            float hv = v[q] * rstd * g[k] + bta[k];
            shnT[k][wv] = hv;
            hn[row * HH + k] = hv;
        }
    }
    __syncthreads();

    float ai0 = eb1l[tid], ai1 = ai0;
    float aj0 = 0.f, aj1 = 0.f;
    for (int c = 0; c < HH; ++c) {
        float wi = ew1l[c * HH + tid];
        float wj = ew1l[(HH + c) * HH + tid];
        float2 s = *(const float2*)&shnT[c][0];
        ai0 += s.x * wi; ai1 += s.y * wi;
        aj0 += s.x * wj; aj1 += s.y * wj;
    }
    Ai[(base + 0) * HH + tid] = ai0; AjB[(base + 0) * HH + tid] = f2bf(aj0);
    Ai[(base + 1) * HH + tid] = ai1; AjB[(base + 1) * HH + tid] = f2bf(aj1);
}

// ---------------------------------------------------------------- fused edge pipeline (MFMA)
// 256 threads = 4 waves; grid 1024 = (b, i, j-half). Each block: 128 j's in
// 4 chunks of 32 rows. LDS 33KB + VGPR<=128 -> 4 blocks/CU = 4 independent
// barrier domains overlapping each other's phase stalls.
__global__ __launch_bounds__(256, 4) void k_edge(
    const float* __restrict__ x, const float* __restrict__ Ai, const unsigned short* __restrict__ AjB,
    const float* __restrict__ wd, const float* __restrict__ eb2v,
    const unsigned short* __restrict__ ew2P, const unsigned short* __restrict__ cw1P,
    const float* __restrict__ cb1v, const float* __restrict__ cw2v, const float* __restrict__ cb2p,
    float* __restrict__ maggH, float* __restrict__ xdeltaH) {
    __shared__ float cwpart[4][32];
    __shared__ unsigned short s_tile[32 * 256];  // rows of 512B, XOR ((row&7)<<4)
    __shared__ unsigned short m_tile[32 * 256];

    int tid = threadIdx.x, wv = tid >> 6, lane = tid & 63;
    int g4 = lane >> 4, l15 = lane & 15;
    int bi = blockIdx.x;
    int half = bi & 1;
    int i = (bi >> 1) & 255;
    int b = bi >> 9;
    int ni = b * NN + i;
    int jb = b * NN + half * 128;

    int k0p = (tid & 31) << 3;
    float aiv[8], wdv[8];
    {
        float4v a0 = *(const float4v*)(Ai + (size_t)ni * HH + k0p);
        float4v a1 = *(const float4v*)(Ai + (size_t)ni * HH + k0p + 4);
        float4v w0 = *(const float4v*)(wd + k0p);
        float4v w1 = *(const float4v*)(wd + k0p + 4);
        #pragma unroll
        for (int e = 0; e < 4; ++e) { aiv[e] = a0[e]; aiv[4 + e] = a1[e]; wdv[e] = w0[e]; wdv[4 + e] = w1[e]; }
    }
    float eb2r[4], cb1r[4], cw2r[4];
    #pragma unroll
    for (int cc = 0; cc < 4; ++cc) {
        int col = wv * 64 + (cc >> 1) * 32 + (cc & 1) * 16 + l15;
        eb2r[cc] = eb2v[col]; cb1r[cc] = cb1v[col]; cw2r[cc] = cw2v[col];
    }
    float xi0 = x[ni * 3 + 0], xi1 = x[ni * 3 + 1], xi2 = x[ni * 3 + 2];
    float cb2 = cb2p[0];

    float mg[4] = {0.f, 0.f, 0.f, 0.f};
    float xd0 = 0.f, xd1 = 0.f, xd2 = 0.f;

    #pragma unroll 1
    for (int jc = 0; jc < 4; ++jc) {
        int j0 = jc * 32;

        // ---- phase 1: s tile = silu(Ai + Aj + d2*wd), 32x256 bf16 (d2 inline)
        #pragma unroll
        for (int it = 0; it < 4; ++it) {
            int row = it * 8 + (tid >> 5);
            int j = jb + j0 + row;
            float rx = xi0 - x[j * 3 + 0];
            float ry = xi1 - x[j * 3 + 1];
            float rz = xi2 - x[j * 3 + 2];
            float d2v = rx * rx + ry * ry + rz * rz;
            u32x4 ajw = *(const u32x4*)(AjB + ((size_t)j * HH + k0p));
            unsigned int uw0, uw1, uw2, uw3;
            {
                float alo = bitsf(ajw[0] << 16), ahi = bitsf(ajw[0] & 0xffff0000u);
                uw0 = cvtpk(fsilu(aiv[0] + alo + d2v * wdv[0]), fsilu(aiv[1] + ahi + d2v * wdv[1]));
            }
            {
                float alo = bitsf(ajw[1] << 16), ahi = bitsf(ajw[1] & 0xffff0000u);
                uw1 = cvtpk(fsilu(aiv[2] + alo + d2v * wdv[2]), fsilu(aiv[3] + ahi + d2v * wdv[3]));
            }
            {
                float alo = bitsf(ajw[2] << 16), ahi = bitsf(ajw[2] & 0xffff0000u);
                uw2 = cvtpk(fsilu(aiv[4] + alo + d2v * wdv[4]), fsilu(aiv[5] + ahi + d2v * wdv[5]));
            }
            {
                float alo = bitsf(ajw[3] << 16), ahi = bitsf(ajw[3] & 0xffff0000u);
                uw3 = cvtpk(fsilu(aiv[6] + alo + d2v * wdv[6]), fsilu(aiv[7] + ahi + d2v * wdv[7]));
            }
            u32x4 sv = {uw0, uw1, uw2, uw3};
            unsigned off = (unsigned)(row * 512 + k0p * 2) ^ (unsigned)((row & 7) << 4);
            *reinterpret_cast<u32x4*>(reinterpret_cast<char*>(s_tile) + off) = sv;
        }
        __syncthreads();

        // ---- phase 2: m = silu(s @ ew2 + eb2), two ct-passes
        #pragma unroll 1
        for (int ctp = 0; ctp < 2; ++ctp) {
            f32x4 acc[2][2];
            acc[0][0] = (f32x4){0.f,0.f,0.f,0.f}; acc[0][1] = (f32x4){0.f,0.f,0.f,0.f};
            acc[1][0] = (f32x4){0.f,0.f,0.f,0.f}; acc[1][1] = (f32x4){0.f,0.f,0.f,0.f};
            int bofs = ((wv * 4 + ctp * 2) << 9) + (lane << 3);
            bf16x8 bc0 = *(const bf16x8*)(ew2P + bofs);
            bf16x8 bc1 = *(const bf16x8*)(ew2P + 512 + bofs);
            #pragma unroll
            for (int ks = 0; ks < 8; ++ks) {
                bf16x8 bn0, bn1;
                if (ks < 7) {
                    bn0 = *(const bf16x8*)(ew2P + ((ks + 1) << 13) + bofs);
                    bn1 = *(const bf16x8*)(ew2P + ((ks + 1) << 13) + 512 + bofs);
                }
                int ak = ks * 32 + g4 * 8;
                int row0 = l15, row1 = l15 + 16;
                unsigned off0 = (unsigned)(row0 * 512 + ak * 2) ^ (unsigned)((row0 & 7) << 4);
                unsigned off1 = (unsigned)(row1 * 512 + ak * 2) ^ (unsigned)((row1 & 7) << 4);
                bf16x8 a0 = *reinterpret_cast<const bf16x8*>(reinterpret_cast<const char*>(s_tile) + off0);
                bf16x8 a1 = *reinterpret_cast<const bf16x8*>(reinterpret_cast<const char*>(s_tile) + off1);
                acc[0][0] = __builtin_amdgcn_mfma_f32_16x16x32_bf16(a0, bc0, acc[0][0], 0, 0, 0);
                acc[0][1] = __builtin_amdgcn_mfma_f32_16x16x32_bf16(a0, bc1, acc[0][1], 0, 0, 0);
                acc[1][0] = __builtin_amdgcn_mfma_f32_16x16x32_bf16(a1, bc0, acc[1][0], 0, 0, 0);
                acc[1][1] = __builtin_amdgcn_mfma_f32_16x16x32_bf16(a1, bc1, acc[1][1], 0, 0, 0);
                if (ks < 7) { bc0 = bn0; bc1 = bn1; }
            }
            int cc0 = ctp * 2, cc1 = ctp * 2 + 1;
            int col0 = wv * 64 + ctp * 32 + l15;
            #pragma unroll
            for (int rt = 0; rt < 2; ++rt) {
                #pragma unroll
                for (int r = 0; r < 4; ++r) {
                    int row = rt * 16 + g4 * 4 + r;
                    float v0 = fsilu(acc[rt][0][r] + eb2r[cc0]);
                    float v1 = fsilu(acc[rt][1][r] + eb2r[cc1]);
                    mg[cc0] += v0; mg[cc1] += v1;
                    unsigned int w = cvtpk(v0, v1);
                    unsigned swz = (unsigned)((row & 7) << 4);
                    unsigned o0 = (unsigned)(row * 512 + col0 * 2) ^ swz;
                    unsigned o1 = (unsigned)(row * 512 + (col0 + 16) * 2) ^ swz;
                    *reinterpret_cast<unsigned short*>(reinterpret_cast<char*>(m_tile) + o0) = (unsigned short)w;
                    *reinterpret_cast<unsigned short*>(reinterpret_cast<char*>(m_tile) + o1) = (unsigned short)(w >> 16);
                }
            }
        }
        __syncthreads();

        // ---- phase 3: c = silu(m @ cw1 + cb1); row-dot with cw2
        {
            float rs[8];
            #pragma unroll
            for (int q = 0; q < 8; ++q) rs[q] = 0.f;
            #pragma unroll 1
            for (int ctp = 0; ctp < 2; ++ctp) {
                f32x4 acc[2][2];
                acc[0][0] = (f32x4){0.f,0.f,0.f,0.f}; acc[0][1] = (f32x4){0.f,0.f,0.f,0.f};
                acc[1][0] = (f32x4){0.f,0.f,0.f,0.f}; acc[1][1] = (f32x4){0.f,0.f,0.f,0.f};
                int bofs = ((wv * 4 + ctp * 2) << 9) + (lane << 3);
                bf16x8 bc0 = *(const bf16x8*)(cw1P + bofs);
                bf16x8 bc1 = *(const bf16x8*)(cw1P + 512 + bofs);
                #pragma unroll
                for (int ks = 0; ks < 8; ++ks) {
                    bf16x8 bn0, bn1;
                    if (ks < 7) {
                        bn0 = *(const bf16x8*)(cw1P + ((ks + 1) << 13) + bofs);
                        bn1 = *(const bf16x8*)(cw1P + ((ks + 1) << 13) + 512 + bofs);
                    }
                    int ak = ks * 32 + g4 * 8;
                    int row0 = l15, row1 = l15 + 16;
                    unsigned off0 = (unsigned)(row0 * 512 + ak * 2) ^ (unsigned)((row0 & 7) << 4);
                    unsigned off1 = (unsigned)(row1 * 512 + ak * 2) ^ (unsigned)((row1 & 7) << 4);
                    bf16x8 a0 = *reinterpret_cast<const bf16x8*>(reinterpret_cast<const char*>(m_tile) + off0);
                    bf16x8 a1 = *reinterpret_cast<const bf16x8*>(reinterpret_cast<const char*>(m_tile) + off1);
                    acc[0][0] = __builtin_amdgcn_mfma_f32_16x16x32_bf16(a0, bc0, acc[0][0], 0, 0, 0);
                    acc[0][1] = __builtin_amdgcn_mfma_f32_16x16x32_bf16(a0, bc1, acc[0][1], 0, 0, 0);
                    acc[1][0] = __builtin_amdgcn_mfma_f32_16x16x32_bf16(a1, bc0, acc[1][0], 0, 0, 0);
                    acc[1][1] = __builtin_amdgcn_mfma_f32_16x16x32_bf16(a1, bc1, acc[1][1], 0, 0, 0);
                    if (ks < 7) { bc0 = bn0; bc1 = bn1; }
                }
                int cc0 = ctp * 2, cc1 = ctp * 2 + 1;
                #pragma unroll
                for (int rt = 0; rt < 2; ++rt)
                    #pragma unroll
                    for (int r = 0; r < 4; ++r)
                        rs[rt * 4 + r] += fsilu(acc[rt][0][r] + cb1r[cc0]) * cw2r[cc0]
                                        + fsilu(acc[rt][1][r] + cb1r[cc1]) * cw2r[cc1];
            }
            #pragma unroll
            for (int m = 1; m <= 8; m <<= 1)
                #pragma unroll
                for (int q = 0; q < 8; ++q) rs[q] += __shfl_xor(rs[q], m);
            if (l15 == 0) {
                #pragma unroll
                for (int rt = 0; rt < 2; ++rt)
                    #pragma unroll
                    for (int r = 0; r < 4; ++r)
                        cwpart[wv][rt * 16 + g4 * 4 + r] = rs[rt * 4 + r];
            }
        }
        __syncthreads();

        if (tid < 32) {
            float cwv = cb2 + cwpart[0][tid] + cwpart[1][tid] + cwpart[2][tid] + cwpart[3][tid];
            int j = jb + j0 + tid;
            float p0 = (xi0 - x[j * 3 + 0]) * cwv;
            float p1 = (xi1 - x[j * 3 + 1]) * cwv;
            float p2 = (xi2 - x[j * 3 + 2]) * cwv;
            #pragma unroll
            for (int m = 1; m < 32; m <<= 1) {
                p0 += __shfl_xor(p0, m); p1 += __shfl_xor(p1, m); p2 += __shfl_xor(p2, m);
            }
            xd0 += p0; xd1 += p1; xd2 += p2;
        }
    }

    #pragma unroll
    for (int cc = 0; cc < 4; ++cc) {
        mg[cc] += __shfl_xor(mg[cc], 16);
        mg[cc] += __shfl_xor(mg[cc], 32);
    }
    if (lane < 16) {
        #pragma unroll
        for (int cc = 0; cc < 4; ++cc)
            maggH[(size_t)half * RN + (size_t)ni * HH + wv * 64 + (cc >> 1) * 32 + (cc & 1) * 16 + lane] = mg[cc];
    }
    if (tid == 0) {
        xdeltaH[half * 2048 + ni * 3 + 0] = xd0 * (1.0f / NN);
        xdeltaH[half * 2048 + ni * 3 + 1] = xd1 * (1.0f / NN);
        xdeltaH[half * 2048 + ni * 3 + 2] = xd2 * (1.0f / NN);
    }
}

// ---------------------------------------------------------------- fused node update + next-layer LN/Ai/Aj
// 2 rows/block, 256 blocks (all CUs), transposed-broadcast LDS staging.
__global__ __launch_bounds__(256) void k_node_ln(
    const float* __restrict__ hn, const float* __restrict__ magg,
    const float* __restrict__ nw1l, const float* __restrict__ nb1l,
    const float* __restrict__ nw2l, const float* __restrict__ nb2l,
    float* __restrict__ h, float* __restrict__ x, const float* __restrict__ xdeltaH,
    const float* __restrict__ g, const float* __restrict__ bta,
    const float* __restrict__ ew1l, const float* __restrict__ eb1l,
    float* __restrict__ hnout, float* __restrict__ Ai, unsigned short* __restrict__ AjB,
    int has_ln) {
    __shared__ float s2T[2 * HH][2];
    __shared__ float suT[HH][2];
    __shared__ float sh[2][HH];
    __shared__ float shnT[HH][2];
    int tid = threadIdx.x;
    int base = blockIdx.x * 2;
    #pragma unroll
    for (int r = 0; r < 2; ++r) {
        s2T[tid][r] = hn[(base + r) * HH + tid];
        s2T[HH + tid][r] = magg[(base + r) * HH + tid] + magg[RN + (base + r) * HH + tid];
    }
    if (tid < 6) {
        int r = tid / 3, c = tid % 3;
        x[(base + r) * 3 + c] += xdeltaH[(base + r) * 3 + c] + xdeltaH[2048 + (base + r) * 3 + c];
    }
    __syncthreads();
    float a0 = nb1l[tid], a1 = a0;
    for (int c = 0; c < 2 * HH; ++c) {
        float w = nw1l[c * HH + tid];
        float2 s = *(const float2*)&s2T[c][0];
        a0 += s.x * w; a1 += s.y * w;
    }
    suT[tid][0] = fsilu(a0); suT[tid][1] = fsilu(a1);
    __syncthreads();
    float d0 = nb2l[tid], d1 = d0;
    for (int c = 0; c < HH; ++c) {
        float w = nw2l[c * HH + tid];
        float2 s = *(const float2*)&suT[c][0];
        d0 += s.x * w; d1 += s.y * w;
    }
    float h0 = h[(base + 0) * HH + tid] + d0;
    float h1 = h[(base + 1) * HH + tid] + d1;
    h[(base + 0) * HH + tid] = h0;
    h[(base + 1) * HH + tid] = h1;
    if (!has_ln) return;
    sh[0][tid] = h0; sh[1][tid] = h1;
    __syncthreads();

    int wv = tid >> 6, lane = tid & 63;
    if (wv < 2) {
        int row = base + wv;
        float v[4];
        #pragma unroll
        for (int q = 0; q < 4; ++q) v[q] = sh[wv][lane + 64 * q];
        float s = v[0] + v[1] + v[2] + v[3];
        #pragma unroll
        for (int m = 1; m < 64; m <<= 1) s += __shfl_xor(s, m);
        float mu = s * (1.0f / HH);
        float var = 0.f;
        #pragma unroll
        for (int q = 0; q < 4; ++q) { v[q] -= mu; var += v[q] * v[q]; }
        #pragma unroll
        for (int m = 1; m < 64; m <<= 1) var += __shfl_xor(var, m);
        float rstd = rsqrtf(var * (1.0f / HH) + 1e-5f);
        #pragma unroll
        for (int q = 0; q < 4; ++q) {
            int k = lane + 64 * q;
            float hv = v[q] * rstd * g[k] + bta[k];
            shnT[k][wv] = hv;
            hnout[row * HH + k] = hv;
        }
    }
    __syncthreads();

    float ai0 = eb1l[tid], ai1 = ai0;
    float aj0 = 0.f, aj1 = 0.f;
    for (int c = 0; c < HH; ++c) {
        float wi = ew1l[c * HH + tid];
        float wj = ew1l[(HH + c) * HH + tid];
        float2 s = *(const float2*)&shnT[c][0];
        ai0 += s.x * wi; ai1 += s.y * wi;
        aj0 += s.x * wj; aj1 += s.y * wj;
    }
    Ai[(base + 0) * HH + tid] = ai0; AjB[(base + 0) * HH + tid] = f2bf(aj0);
    Ai[(base + 1) * HH + tid] = ai1; AjB[(base + 1) * HH + tid] = f2bf(aj1);
}

// ---------------------------------------------------------------- decoder (2 rows/block)
__global__ __launch_bounds__(256) void k_decoder(
    const float* __restrict__ h,
    const float* __restrict__ dw1, const float* __restrict__ db1,
    const float* __restrict__ dw2, const float* __restrict__ db2,
    const float* __restrict__ dw3, const float* __restrict__ db3,
    float* __restrict__ out) {
    __shared__ float shT[HH][2];
    __shared__ float so1T[HH][2];
    __shared__ float so2T[HH][2];
    int tid = threadIdx.x;
    int base = blockIdx.x * 2;
    #pragma unroll
    for (int r = 0; r < 2; ++r) shT[tid][r] = h[(base + r) * HH + tid];
    __syncthreads();
    float a0 = db1[tid], a1 = a0;
    for (int c = 0; c < HH; ++c) {
        float w = dw1[c * HH + tid];
        float2 s = *(const float2*)&shT[c][0];
        a0 += s.x * w; a1 += s.y * w;
    }
    so1T[tid][0] = fmaxf(a0, 0.f); so1T[tid][1] = fmaxf(a1, 0.f);
    __syncthreads();
    a0 = db2[tid]; a1 = a0;
    for (int c = 0; c < HH; ++c) {
        float w = dw2[c * HH + tid];
        float2 s = *(const float2*)&so1T[c][0];
        a0 += s.x * w; a1 += s.y * w;
    }
    so2T[tid][0] = fmaxf(a0, 0.f) + shT[tid][0];
    so2T[tid][1] = fmaxf(a1, 0.f) + shT[tid][1];
    __syncthreads();
    if (tid < 6) {
        int r = tid / 3, c = tid % 3;
        float acc = db3[c];
        for (int k = 0; k < HH; ++k) acc += so2T[k][r] * dw3[k * 3 + c];
        out[(base + r) * 3 + c] = acc;
    }
}

// ---------------------------------------------------------------- launch
extern "C" void kernel_launch(void* const* d_in, const int* in_sizes, int n_in,
                              void* d_out, int out_size, void* d_ws, size_t ws_size,
                              hipStream_t stream) {
    const float* coords = (const float*)d_in[0];
    const float* feats  = (const float*)d_in[1];
    const float* t      = (const float*)d_in[2];
    const float* pe_w1  = (const float*)d_in[3];  const float* pe_b1 = (const float*)d_in[4];
    const float* pe_w2  = (const float*)d_in[5];  const float* pe_b2 = (const float*)d_in[6];
    const float* pe_w3  = (const float*)d_in[7];  const float* pe_b3 = (const float*)d_in[8];
    const float* te_w1  = (const float*)d_in[9];  const float* te_b1 = (const float*)d_in[10];
    const float* te_w2  = (const float*)d_in[11]; const float* te_b2 = (const float*)d_in[12];
    const float* ln_g   = (const float*)d_in[13]; const float* ln_b  = (const float*)d_in[14];
    const float* ew1    = (const float*)d_in[15]; const float* eb1   = (const float*)d_in[16];
    const float* ew2    = (const float*)d_in[17]; const float* eb2   = (const float*)d_in[18];
    const float* cw1    = (const float*)d_in[19]; const float* cb1   = (const float*)d_in[20];
    const float* cw2    = (const float*)d_in[21]; const float* cb2   = (const float*)d_in[22];
    const float* nw1    = (const float*)d_in[23]; const float* nb1   = (const float*)d_in[24];
    const float* nw2    = (const float*)d_in[25]; const float* nb2   = (const float*)d_in[26];
    const float* dec_w1 = (const float*)d_in[27]; const float* dec_b1 = (const float*)d_in[28];
    const float* dec_w2 = (const float*)d_in[29]; const float* dec_b2 = (const float*)d_in[30];
    const float* dec_w3 = (const float*)d_in[31]; const float* dec_b3 = (const float*)d_in[32];

    float* ws = (float*)d_ws;
    float* h      = ws;
    float* hn     = ws + RN;
    float* Ai     = ws + 2 * RN;
    float* magg   = ws + 3 * RN;            // 2*RN (two halves)
    float* x      = ws + 5 * RN;            // 1536 (reserve 2048)
    float* xdelta = ws + 5 * RN + 2048;     // 2*2048 (two halves)
    unsigned short* AjB  = (unsigned short*)(ws + 5 * RN + 2048 + 4096);
    unsigned short* ew2P = AjB + RN;
    unsigned short* cw1P = ew2P + LL * HH * HH;

    k_convert<<<(LL * 8192 + 511) / 512, 512, 0, stream>>>(ew2, cw1, ew2P, cw1P);
    k_encoder<<<NB * NN / 2, 256, 0, stream>>>(coords, feats, t,
        pe_w1, pe_b1, pe_w2, pe_b2, pe_w3, pe_b3, te_w1, te_b1, te_w2, te_b2, h, x);
    k_ln_aiaj<<<NB * NN / 2, 256, 0, stream>>>(h, ln_g, ln_b, ew1, eb1, hn, Ai, AjB);

    for (int l = 0; l < LL; ++l) {
        k_edge<<<NB * NN * 2, 256, 0, stream>>>(x, Ai, AjB,
            ew1 + ((size_t)l * 513 + 512) * HH, eb2 + l * HH,
            ew2P + (size_t)l * HH * HH, cw1P + (size_t)l * HH * HH,
            cb1 + l * HH, cw2 + l * HH, cb2 + l, magg, xdelta);
        int ln = (l + 1 < LL) ? (l + 1) : LL - 1;  // params unused when has_ln=0
        k_node_ln<<<NB * NN / 2, 256, 0, stream>>>(hn, magg,
            nw1 + (size_t)l * 2 * HH * HH, nb1 + l * HH,
            nw2 + (size_t)l * HH * HH, nb2 + l * HH, h, x, xdelta,
            ln_g + ln * HH, ln_b + ln * HH,
            ew1 + (size_t)ln * 513 * HH, eb1 + ln * HH,
            hn, Ai, AjB, (l + 1 < LL) ? 1 : 0);
    }

    k_decoder<<<NB * NN / 2, 256, 0, stream>>>(h, dec_w1, dec_b1, dec_w2, dec_b2,
                                               dec_w3, dec_b3, (float*)d_out);
}

// Round 9
// 694.738 us; speedup vs baseline: 1.6096x; 1.6096x over previous
//
#include <hip/hip_runtime.h>
#include <math.h>

static constexpr int NB = 2, NN = 256, HH = 256, DD = 64, LL = 6;
static constexpr int RN = NB * NN * HH;  // 131072

typedef __attribute__((ext_vector_type(8))) short bf16x8;
typedef __attribute__((ext_vector_type(4))) float f32x4;
typedef __attribute__((ext_vector_type(4))) float float4v;
typedef __attribute__((ext_vector_type(4))) unsigned int u32x4;

// fast silu: v * rcp(1+exp(-v)) — avoids the ~12-inst IEEE div lowering
__device__ __forceinline__ float fsilu(float v) {
    return v * __builtin_amdgcn_rcpf(1.0f + __expf(-v));
}
__device__ __forceinline__ unsigned short f2bf(float f) {
    union { float f; unsigned int u; } x; x.f = f;
    unsigned int r = x.u + 0x7fffu + ((x.u >> 16) & 1u);
    return (unsigned short)(r >> 16);
}
__device__ __forceinline__ float bitsf(unsigned int u) {
    union { float f; unsigned int u; } x; x.u = u; return x.f;
}
__device__ __forceinline__ unsigned int cvtpk(float lo, float hi) {
    unsigned int w;
    asm("v_cvt_pk_bf16_f32 %0, %1, %2" : "=v"(w) : "v"(lo), "v"(hi));
    return w;
}

// ---------------------------------------------------------------- convert (fragment-packed)
// elem[(l*8192 + (ks*16 + wv*2 + ct)*64 + lane)*8 + e]
//   = bf16( W[l][ k = ks*32+(lane>>4)*8+e ][ col = wv*32+ct*16+(lane&15) ] )
__global__ void k_convert(const float* __restrict__ ew2, const float* __restrict__ cw1,
                          unsigned short* __restrict__ ew2P, unsigned short* __restrict__ cw1P) {
    int g = blockIdx.x * blockDim.x + threadIdx.x;
    if (g >= LL * 8192) return;
    int l = g >> 13;
    int r = g & 8191;
    int lane = r & 63;
    int fidx = r >> 6;
    int ks = fidx >> 4;
    int wv = (fidx >> 1) & 7;
    int ct = fidx & 1;
    int col = wv * 32 + ct * 16 + (lane & 15);
    int k0 = ks * 32 + (lane >> 4) * 8;
    #pragma unroll
    for (int e = 0; e < 8; ++e) {
        ew2P[(size_t)g * 8 + e] = f2bf(ew2[((size_t)l * HH + k0 + e) * HH + col]);
        cw1P[(size_t)g * 8 + e] = f2bf(cw1[((size_t)l * HH + k0 + e) * HH + col]);
    }
}

// ---------------------------------------------------------------- encoder (2 rows/block, broadcast staging)
__global__ __launch_bounds__(256) void k_encoder(
    const float* __restrict__ coords, const float* __restrict__ feats, const float* __restrict__ t,
    const float* __restrict__ pw1, const float* __restrict__ pb1,
    const float* __restrict__ pw2, const float* __restrict__ pb2,
    const float* __restrict__ pw3, const float* __restrict__ pb3,
    const float* __restrict__ tw1, const float* __restrict__ tb1,
    const float* __restrict__ tw2, const float* __restrict__ tb2,
    float* __restrict__ h, float* __restrict__ x) {
    __shared__ float spinT[68][2];
    __shared__ float shaT[HH][2];
    __shared__ float shbT[HH][2];
    __shared__ float ste1[HH];
    int tid = threadIdx.x;
    int base = blockIdx.x * 2;
    int b = base / NN;

    #pragma unroll
    for (int r = 0; r < 2; ++r) {
        int row = base + r;
        if (tid < 3) spinT[tid][r] = coords[row * 3 + tid];
        if (tid < DD) spinT[3 + tid][r] = feats[row * DD + tid];
    }
    float tv = t[b];
    ste1[tid] = fmaxf(tv * tw1[tid] + tb1[tid], 0.0f);
    if (tid < 6) {
        int r = tid / 3, c = tid % 3;
        x[(base + r) * 3 + c] = coords[(base + r) * 3 + c];
    }
    __syncthreads();

    float a0 = pb1[tid], a1 = a0;
    for (int c = 0; c < 67; ++c) {
        float w = pw1[c * HH + tid];
        float2 s = *(const float2*)&spinT[c][0];
        a0 += s.x * w; a1 += s.y * w;
    }
    shaT[tid][0] = fmaxf(a0, 0.f); shaT[tid][1] = fmaxf(a1, 0.f);
    __syncthreads();
    a0 = pb2[tid]; a1 = a0;
    for (int c = 0; c < HH; ++c) {
        float w = pw2[c * HH + tid];
        float2 s = *(const float2*)&shaT[c][0];
        a0 += s.x * w; a1 += s.y * w;
    }
    shbT[tid][0] = fmaxf(a0, 0.f); shbT[tid][1] = fmaxf(a1, 0.f);
    __syncthreads();
    a0 = pb3[tid]; a1 = a0;
    float te = tb2[tid];
    for (int c = 0; c < HH; ++c) {
        float w = pw3[c * HH + tid];
        float2 s = *(const float2*)&shbT[c][0];
        a0 += s.x * w; a1 += s.y * w;
        te += ste1[c] * tw2[c * HH + tid];
    }
    h[(base + 0) * HH + tid] = fmaxf(a0, 0.f) + te;
    h[(base + 1) * HH + tid] = fmaxf(a1, 0.f) + te;
}

// ---------------------------------------------------------------- LayerNorm + Ai/Aj (layer 0, 2 rows/block)
__global__ __launch_bounds__(256) void k_ln_aiaj(
    const float* __restrict__ h, const float* __restrict__ g, const float* __restrict__ bta,
    const float* __restrict__ ew1l, const float* __restrict__ eb1l,
    float* __restrict__ hn, float* __restrict__ Ai, unsigned short* __restrict__ AjB) {
    __shared__ float shnT[HH][2];
    int tid = threadIdx.x, wv = tid >> 6, lane = tid & 63;
    int base = blockIdx.x * 2;

    if (wv < 2) {
        int row = base + wv;
        float v[4];
        #pragma unroll
        for (int q = 0; q < 4; ++q) v[q] = h[row * HH + lane + 64 * q];
        float s = v[0] + v[1] + v[2] + v[3];
        #pragma unroll
        for (int m = 1; m < 64; m <<= 1) s += __shfl_xor(s, m);
        float mu = s * (1.0f / HH);
        float var = 0.f;
        #pragma unroll
        for (int q = 0; q < 4; ++q) { v[q] -= mu; var += v[q] * v[q]; }
        #pragma unroll
        for (int m = 1; m < 64; m <<= 1) var += __shfl_xor(var, m);
        float rstd = rsqrtf(var * (1.0f / HH) + 1e-5f);
        #pragma unroll
        for (int q = 0; q < 4; ++q) {
            int k = lane + 64 * q;
            float hv = v[q] * rstd * g[k] + bta[k];
            shnT[k][wv] = hv;
            hn[row * HH + k] = hv;
        }
    }
    __syncthreads();

    float ai0 = eb1l[tid], ai1 = ai0;
    float aj0 = 0.f, aj1 = 0.f;
    for (int c = 0; c < HH; ++c) {
        float wi = ew1l[c * HH + tid];
        float wj = ew1l[(HH + c) * HH + tid];
        float2 s = *(const float2*)&shnT[c][0];
        ai0 += s.x * wi; ai1 += s.y * wi;
        aj0 += s.x * wj; aj1 += s.y * wj;
    }
    Ai[(base + 0) * HH + tid] = ai0; AjB[(base + 0) * HH + tid] = f2bf(aj0);
    Ai[(base + 1) * HH + tid] = ai1; AjB[(base + 1) * HH + tid] = f2bf(aj1);
}

// ---------------------------------------------------------------- fused edge pipeline (MFMA)
// EXACT round-7 structure (87us/dispatch, VGPR 124, no spill).
// 512 threads = 8 waves, one block per (b,i). Wave owns 32 output cols.
// __launch_bounds__(512, 1): arg2 is min BLOCKS/CU (CUDA-style) on hipcc —
// any higher value caps regalloc (128 or 64) and spills 55-110MB/dispatch
// (rounds 2-5, 8). DO NOT TOUCH.
__global__ __launch_bounds__(512, 1) void k_edge(
    const float* __restrict__ x, const float* __restrict__ Ai, const unsigned short* __restrict__ AjB,
    const float* __restrict__ wd, const float* __restrict__ eb2v,
    const unsigned short* __restrict__ ew2P, const unsigned short* __restrict__ cw1P,
    const float* __restrict__ cb1v, const float* __restrict__ cw2v, const float* __restrict__ cb2p,
    float* __restrict__ magg, float* __restrict__ xdelta) {
    __shared__ float srel[64][3];
    __shared__ float sd2[64];
    __shared__ float cwpart[8][64];
    __shared__ unsigned short s_tile[64 * 256];  // rows of 512B, XOR ((row&7)<<4)
    __shared__ unsigned short m_tile[64 * 256];

    int tid = threadIdx.x, wv = tid >> 6, lane = tid & 63;
    int g4 = lane >> 4, l15 = lane & 15;
    int colbase = wv * 32;
    int bi = blockIdx.x;
    int b = bi >> 8, i = bi & 255;
    int ni = b * NN + i;
    int bbase = b * NN;
    int bthr = ((wv << 7) + lane) << 3;  // packed-B elem offset; (ks,ct) adds (ks<<13)+(ct<<9)

    int k0p = (tid & 31) << 3;
    float aiv[8], wdv[8];
    {
        float4v a0 = *(const float4v*)(Ai + (size_t)ni * HH + k0p);
        float4v a1 = *(const float4v*)(Ai + (size_t)ni * HH + k0p + 4);
        float4v w0 = *(const float4v*)(wd + k0p);
        float4v w1 = *(const float4v*)(wd + k0p + 4);
        #pragma unroll
        for (int e = 0; e < 4; ++e) { aiv[e] = a0[e]; aiv[4 + e] = a1[e]; wdv[e] = w0[e]; wdv[4 + e] = w1[e]; }
    }
    float eb2r[2], cb1r[2], cw2r[2];
    #pragma unroll
    for (int ct = 0; ct < 2; ++ct) {
        int col = colbase + ct * 16 + l15;
        eb2r[ct] = eb2v[col]; cb1r[ct] = cb1v[col]; cw2r[ct] = cw2v[col];
    }
    float xi0 = x[ni * 3 + 0], xi1 = x[ni * 3 + 1], xi2 = x[ni * 3 + 2];
    float cb2 = cb2p[0];

    float mg[2] = {0.f, 0.f};
    float xd0 = 0.f, xd1 = 0.f, xd2 = 0.f;

    #pragma unroll 1
    for (int jc = 0; jc < 4; ++jc) {
        int j0 = jc * 64;
        __syncthreads();
        if (tid < 64) {
            int j = bbase + j0 + tid;
            float rx = xi0 - x[j * 3 + 0];
            float ry = xi1 - x[j * 3 + 1];
            float rz = xi2 - x[j * 3 + 2];
            srel[tid][0] = rx; srel[tid][1] = ry; srel[tid][2] = rz;
            sd2[tid] = rx * rx + ry * ry + rz * rz;
        }
        __syncthreads();

        // ---- phase 1: s tile = silu(Ai + Aj + d2*wd), 64x256 bf16
        #pragma unroll
        for (int it = 0; it < 4; ++it) {
            int row = it * 16 + (tid >> 5);
            float d2v = sd2[row];
            u32x4 ajw = *(const u32x4*)(AjB + ((size_t)(bbase + j0 + row) * HH + k0p));
            unsigned int uw0, uw1, uw2, uw3;
            {
                float alo = bitsf(ajw[0] << 16), ahi = bitsf(ajw[0] & 0xffff0000u);
                uw0 = cvtpk(fsilu(aiv[0] + alo + d2v * wdv[0]), fsilu(aiv[1] + ahi + d2v * wdv[1]));
            }
            {
                float alo = bitsf(ajw[1] << 16), ahi = bitsf(ajw[1] & 0xffff0000u);
                uw1 = cvtpk(fsilu(aiv[2] + alo + d2v * wdv[2]), fsilu(aiv[3] + ahi + d2v * wdv[3]));
            }
            {
                float alo = bitsf(ajw[2] << 16), ahi = bitsf(ajw[2] & 0xffff0000u);
                uw2 = cvtpk(fsilu(aiv[4] + alo + d2v * wdv[4]), fsilu(aiv[5] + ahi + d2v * wdv[5]));
            }
            {
                float alo = bitsf(ajw[3] << 16), ahi = bitsf(ajw[3] & 0xffff0000u);
                uw3 = cvtpk(fsilu(aiv[6] + alo + d2v * wdv[6]), fsilu(aiv[7] + ahi + d2v * wdv[7]));
            }
            u32x4 sv = {uw0, uw1, uw2, uw3};
            unsigned off = (unsigned)(row * 512 + k0p * 2) ^ (unsigned)((row & 7) << 4);
            *reinterpret_cast<u32x4*>(reinterpret_cast<char*>(s_tile) + off) = sv;
        }
        __syncthreads();

        // ---- phase 2: m = silu(s @ ew2 + eb2), two 32-row half-passes
        #pragma unroll 1
        for (int rh = 0; rh < 2; ++rh) {
            f32x4 acc[2][2];
            acc[0][0] = (f32x4){0.f,0.f,0.f,0.f}; acc[0][1] = (f32x4){0.f,0.f,0.f,0.f};
            acc[1][0] = (f32x4){0.f,0.f,0.f,0.f}; acc[1][1] = (f32x4){0.f,0.f,0.f,0.f};
            bf16x8 bc0 = *(const bf16x8*)(ew2P + bthr);
            bf16x8 bc1 = *(const bf16x8*)(ew2P + (1 << 9) + bthr);
            #pragma unroll
            for (int ks = 0; ks < 8; ++ks) {
                bf16x8 bn0, bn1;
                if (ks < 7) {
                    bn0 = *(const bf16x8*)(ew2P + ((ks + 1) << 13) + bthr);
                    bn1 = *(const bf16x8*)(ew2P + ((ks + 1) << 13) + (1 << 9) + bthr);
                }
                int ak = ks * 32 + g4 * 8;
                int row0 = rh * 32 + l15;
                int row1 = row0 + 16;
                unsigned off0 = (unsigned)(row0 * 512 + ak * 2) ^ (unsigned)((row0 & 7) << 4);
                unsigned off1 = (unsigned)(row1 * 512 + ak * 2) ^ (unsigned)((row1 & 7) << 4);
                bf16x8 a0 = *reinterpret_cast<const bf16x8*>(reinterpret_cast<const char*>(s_tile) + off0);
                bf16x8 a1 = *reinterpret_cast<const bf16x8*>(reinterpret_cast<const char*>(s_tile) + off1);
                acc[0][0] = __builtin_amdgcn_mfma_f32_16x16x32_bf16(a0, bc0, acc[0][0], 0, 0, 0);
                acc[0][1] = __builtin_amdgcn_mfma_f32_16x16x32_bf16(a0, bc1, acc[0][1], 0, 0, 0);
                acc[1][0] = __builtin_amdgcn_mfma_f32_16x16x32_bf16(a1, bc0, acc[1][0], 0, 0, 0);
                acc[1][1] = __builtin_amdgcn_mfma_f32_16x16x32_bf16(a1, bc1, acc[1][1], 0, 0, 0);
                if (ks < 7) { bc0 = bn0; bc1 = bn1; }
            }
            // epilogue: silu + pack (pair across ct: same row, cols 16 apart)
            #pragma unroll
            for (int rt = 0; rt < 2; ++rt) {
                #pragma unroll
                for (int r = 0; r < 4; ++r) {
                    int row = rh * 32 + rt * 16 + g4 * 4 + r;
                    float v0 = fsilu(acc[rt][0][r] + eb2r[0]);
                    float v1 = fsilu(acc[rt][1][r] + eb2r[1]);
                    mg[0] += v0; mg[1] += v1;
                    unsigned int w = cvtpk(v0, v1);
                    unsigned swz = (unsigned)((row & 7) << 4);
                    unsigned off0 = (unsigned)(row * 512 + (colbase + l15) * 2) ^ swz;
                    unsigned off1 = (unsigned)(row * 512 + (colbase + 16 + l15) * 2) ^ swz;
                    *reinterpret_cast<unsigned short*>(reinterpret_cast<char*>(m_tile) + off0) = (unsigned short)w;
                    *reinterpret_cast<unsigned short*>(reinterpret_cast<char*>(m_tile) + off1) = (unsigned short)(w >> 16);
                }
            }
        }
        __syncthreads();

        // ---- phase 3: c = silu(m @ cw1 + cb1); cw-row-dot with cw2 (two half-passes)
        #pragma unroll 1
        for (int rh = 0; rh < 2; ++rh) {
            f32x4 acc[2][2];
            acc[0][0] = (f32x4){0.f,0.f,0.f,0.f}; acc[0][1] = (f32x4){0.f,0.f,0.f,0.f};
            acc[1][0] = (f32x4){0.f,0.f,0.f,0.f}; acc[1][1] = (f32x4){0.f,0.f,0.f,0.f};
            bf16x8 bc0 = *(const bf16x8*)(cw1P + bthr);
            bf16x8 bc1 = *(const bf16x8*)(cw1P + (1 << 9) + bthr);
            #pragma unroll
            for (int ks = 0; ks < 8; ++ks) {
                bf16x8 bn0, bn1;
                if (ks < 7) {
                    bn0 = *(const bf16x8*)(cw1P + ((ks + 1) << 13) + bthr);
                    bn1 = *(const bf16x8*)(cw1P + ((ks + 1) << 13) + (1 << 9) + bthr);
                }
                int ak = ks * 32 + g4 * 8;
                int row0 = rh * 32 + l15;
                int row1 = row0 + 16;
                unsigned off0 = (unsigned)(row0 * 512 + ak * 2) ^ (unsigned)((row0 & 7) << 4);
                unsigned off1 = (unsigned)(row1 * 512 + ak * 2) ^ (unsigned)((row1 & 7) << 4);
                bf16x8 a0 = *reinterpret_cast<const bf16x8*>(reinterpret_cast<const char*>(m_tile) + off0);
                bf16x8 a1 = *reinterpret_cast<const bf16x8*>(reinterpret_cast<const char*>(m_tile) + off1);
                acc[0][0] = __builtin_amdgcn_mfma_f32_16x16x32_bf16(a0, bc0, acc[0][0], 0, 0, 0);
                acc[0][1] = __builtin_amdgcn_mfma_f32_16x16x32_bf16(a0, bc1, acc[0][1], 0, 0, 0);
                acc[1][0] = __builtin_amdgcn_mfma_f32_16x16x32_bf16(a1, bc0, acc[1][0], 0, 0, 0);
                acc[1][1] = __builtin_amdgcn_mfma_f32_16x16x32_bf16(a1, bc1, acc[1][1], 0, 0, 0);
                if (ks < 7) { bc0 = bn0; bc1 = bn1; }
            }
            float rs[8];
            #pragma unroll
            for (int q = 0; q < 8; ++q) rs[q] = 0.f;
            #pragma unroll
            for (int ct = 0; ct < 2; ++ct) {
                #pragma unroll
                for (int rt = 0; rt < 2; ++rt)
                    #pragma unroll
                    for (int r = 0; r < 4; ++r)
                        rs[rt * 4 + r] += fsilu(acc[rt][ct][r] + cb1r[ct]) * cw2r[ct];
            }
            #pragma unroll
            for (int m = 1; m <= 8; m <<= 1)
                #pragma unroll
                for (int q = 0; q < 8; ++q) rs[q] += __shfl_xor(rs[q], m);
            if (l15 == 0) {
                #pragma unroll
                for (int rt = 0; rt < 2; ++rt)
                    #pragma unroll
                    for (int r = 0; r < 4; ++r)
                        cwpart[wv][rh * 32 + rt * 16 + g4 * 4 + r] = rs[rt * 4 + r];
            }
        }
        __syncthreads();
        if (tid < 64) {
            float cwv = cb2;
            #pragma unroll
            for (int w = 0; w < 8; ++w) cwv += cwpart[w][tid];
            float p0 = srel[tid][0] * cwv;
            float p1 = srel[tid][1] * cwv;
            float p2 = srel[tid][2] * cwv;
            #pragma unroll
            for (int m = 1; m < 64; m <<= 1) {
                p0 += __shfl_xor(p0, m); p1 += __shfl_xor(p1, m); p2 += __shfl_xor(p2, m);
            }
            xd0 += p0; xd1 += p1; xd2 += p2;
        }
    }

    #pragma unroll
    for (int ct = 0; ct < 2; ++ct) {
        mg[ct] += __shfl_xor(mg[ct], 16);
        mg[ct] += __shfl_xor(mg[ct], 32);
    }
    if (lane < 16) {
        #pragma unroll
        for (int ct = 0; ct < 2; ++ct)
            magg[(size_t)ni * HH + colbase + ct * 16 + lane] = mg[ct];
    }
    if (tid == 0) {
        xdelta[ni * 3 + 0] = xd0 * (1.0f / NN);
        xdelta[ni * 3 + 1] = xd1 * (1.0f / NN);
        xdelta[ni * 3 + 2] = xd2 * (1.0f / NN);
    }
}

// ---------------------------------------------------------------- fused node update + next-layer LN/Ai/Aj
// 2 rows/block, 256 blocks (all CUs), transposed-broadcast LDS staging.
__global__ __launch_bounds__(256) void k_node_ln(
    const float* __restrict__ hn, const float* __restrict__ magg,
    const float* __restrict__ nw1l, const float* __restrict__ nb1l,
    const float* __restrict__ nw2l, const float* __restrict__ nb2l,
    float* __restrict__ h, float* __restrict__ x, const float* __restrict__ xdelta,
    const float* __restrict__ g, const float* __restrict__ bta,
    const float* __restrict__ ew1l, const float* __restrict__ eb1l,
    float* __restrict__ hnout, float* __restrict__ Ai, unsigned short* __restrict__ AjB,
    int has_ln) {
    __shared__ float s2T[2 * HH][2];
    __shared__ float suT[HH][2];
    __shared__ float sh[2][HH];
    __shared__ float shnT[HH][2];
    int tid = threadIdx.x;
    int base = blockIdx.x * 2;
    #pragma unroll
    for (int r = 0; r < 2; ++r) {
        s2T[tid][r] = hn[(base + r) * HH + tid];
        s2T[HH + tid][r] = magg[(base + r) * HH + tid];
    }
    if (tid < 6) {
        int r = tid / 3, c = tid % 3;
        x[(base + r) * 3 + c] += xdelta[(base + r) * 3 + c];
    }
    __syncthreads();
    float a0 = nb1l[tid], a1 = a0;
    for (int c = 0; c < 2 * HH; ++c) {
        float w = nw1l[c * HH + tid];
        float2 s = *(const float2*)&s2T[c][0];
        a0 += s.x * w; a1 += s.y * w;
    }
    suT[tid][0] = fsilu(a0); suT[tid][1] = fsilu(a1);
    __syncthreads();
    float d0 = nb2l[tid], d1 = d0;
    for (int c = 0; c < HH; ++c) {
        float w = nw2l[c * HH + tid];
        float2 s = *(const float2*)&suT[c][0];
        d0 += s.x * w; d1 += s.y * w;
    }
    float h0 = h[(base + 0) * HH + tid] + d0;
    float h1 = h[(base + 1) * HH + tid] + d1;
    h[(base + 0) * HH + tid] = h0;
    h[(base + 1) * HH + tid] = h1;
    if (!has_ln) return;
    sh[0][tid] = h0; sh[1][tid] = h1;
    __syncthreads();

    int wv = tid >> 6, lane = tid & 63;
    if (wv < 2) {
        int row = base + wv;
        float v[4];
        #pragma unroll
        for (int q = 0; q < 4; ++q) v[q] = sh[wv][lane + 64 * q];
        float s = v[0] + v[1] + v[2] + v[3];
        #pragma unroll
        for (int m = 1; m < 64; m <<= 1) s += __shfl_xor(s, m);
        float mu = s * (1.0f / HH);
        float var = 0.f;
        #pragma unroll
        for (int q = 0; q < 4; ++q) { v[q] -= mu; var += v[q] * v[q]; }
        #pragma unroll
        for (int m = 1; m < 64; m <<= 1) var += __shfl_xor(var, m);
        float rstd = rsqrtf(var * (1.0f / HH) + 1e-5f);
        #pragma unroll
        for (int q = 0; q < 4; ++q) {
            int k = lane + 64 * q;
            float hv = v[q] * rstd * g[k] + bta[k];
            shnT[k][wv] = hv;
            hnout[row * HH + k] = hv;
        }
    }
    __syncthreads();

    float ai0 = eb1l[tid], ai1 = ai0;
    float aj0 = 0.f, aj1 = 0.f;
    for (int c = 0; c < HH; ++c) {
        float wi = ew1l[c * HH + tid];
        float wj = ew1l[(HH + c) * HH + tid];
        float2 s = *(const float2*)&shnT[c][0];
        ai0 += s.x * wi; ai1 += s.y * wi;
        aj0 += s.x * wj; aj1 += s.y * wj;
    }
    Ai[(base + 0) * HH + tid] = ai0; AjB[(base + 0) * HH + tid] = f2bf(aj0);
    Ai[(base + 1) * HH + tid] = ai1; AjB[(base + 1) * HH + tid] = f2bf(aj1);
}

// ---------------------------------------------------------------- decoder (2 rows/block)
__global__ __launch_bounds__(256) void k_decoder(
    const float* __restrict__ h,
    const float* __restrict__ dw1, const float* __restrict__ db1,
    const float* __restrict__ dw2, const float* __restrict__ db2,
    const float* __restrict__ dw3, const float* __restrict__ db3,
    float* __restrict__ out) {
    __shared__ float shT[HH][2];
    __shared__ float so1T[HH][2];
    __shared__ float so2T[HH][2];
    int tid = threadIdx.x;
    int base = blockIdx.x * 2;
    #pragma unroll
    for (int r = 0; r < 2; ++r) shT[tid][r] = h[(base + r) * HH + tid];
    __syncthreads();
    float a0 = db1[tid], a1 = a0;
    for (int c = 0; c < HH; ++c) {
        float w = dw1[c * HH + tid];
        float2 s = *(const float2*)&shT[c][0];
        a0 += s.x * w; a1 += s.y * w;
    }
    so1T[tid][0] = fmaxf(a0, 0.f); so1T[tid][1] = fmaxf(a1, 0.f);
    __syncthreads();
    a0 = db2[tid]; a1 = a0;
    for (int c = 0; c < HH; ++c) {
        float w = dw2[c * HH + tid];
        float2 s = *(const float2*)&so1T[c][0];
        a0 += s.x * w; a1 += s.y * w;
    }
    so2T[tid][0] = fmaxf(a0, 0.f) + shT[tid][0];
    so2T[tid][1] = fmaxf(a1, 0.f) + shT[tid][1];
    __syncthreads();
    if (tid < 6) {
        int r = tid / 3, c = tid % 3;
        float acc = db3[c];
        for (int k = 0; k < HH; ++k) acc += so2T[k][r] * dw3[k * 3 + c];
        out[(base + r) * 3 + c] = acc;
    }
}

// ---------------------------------------------------------------- launch
extern "C" void kernel_launch(void* const* d_in, const int* in_sizes, int n_in,
                              void* d_out, int out_size, void* d_ws, size_t ws_size,
                              hipStream_t stream) {
    const float* coords = (const float*)d_in[0];
    const float* feats  = (const float*)d_in[1];
    const float* t      = (const float*)d_in[2];
    const float* pe_w1  = (const float*)d_in[3];  const float* pe_b1 = (const float*)d_in[4];
    const float* pe_w2  = (const float*)d_in[5];  const float* pe_b2 = (const float*)d_in[6];
    const float* pe_w3  = (const float*)d_in[7];  const float* pe_b3 = (const float*)d_in[8];
    const float* te_w1  = (const float*)d_in[9];  const float* te_b1 = (const float*)d_in[10];
    const float* te_w2  = (const float*)d_in[11]; const float* te_b2 = (const float*)d_in[12];
    const float* ln_g   = (const float*)d_in[13]; const float* ln_b  = (const float*)d_in[14];
    const float* ew1    = (const float*)d_in[15]; const float* eb1   = (const float*)d_in[16];
    const float* ew2    = (const float*)d_in[17]; const float* eb2   = (const float*)d_in[18];
    const float* cw1    = (const float*)d_in[19]; const float* cb1   = (const float*)d_in[20];
    const float* cw2    = (const float*)d_in[21]; const float* cb2   = (const float*)d_in[22];
    const float* nw1    = (const float*)d_in[23]; const float* nb1   = (const float*)d_in[24];
    const float* nw2    = (const float*)d_in[25]; const float* nb2   = (const float*)d_in[26];
    const float* dec_w1 = (const float*)d_in[27]; const float* dec_b1 = (const float*)d_in[28];
    const float* dec_w2 = (const float*)d_in[29]; const float* dec_b2 = (const float*)d_in[30];
    const float* dec_w3 = (const float*)d_in[31]; const float* dec_b3 = (const float*)d_in[32];

    float* ws = (float*)d_ws;
    float* h      = ws;
    float* hn     = ws + RN;
    float* Ai     = ws + 2 * RN;
    float* magg   = ws + 3 * RN;
    float* x      = ws + 4 * RN;            // 1536 (reserve 2048)
    float* xdelta = ws + 4 * RN + 2048;     // 1536 (reserve 2048)
    unsigned short* AjB  = (unsigned short*)(ws + 4 * RN + 4096);
    unsigned short* ew2P = AjB + RN;
    unsigned short* cw1P = ew2P + LL * HH * HH;

    k_convert<<<(LL * 8192 + 511) / 512, 512, 0, stream>>>(ew2, cw1, ew2P, cw1P);
    k_encoder<<<NB * NN / 2, 256, 0, stream>>>(coords, feats, t,
        pe_w1, pe_b1, pe_w2, pe_b2, pe_w3, pe_b3, te_w1, te_b1, te_w2, te_b2, h, x);
    k_ln_aiaj<<<NB * NN / 2, 256, 0, stream>>>(h, ln_g, ln_b, ew1, eb1, hn, Ai, AjB);

    for (int l = 0; l < LL; ++l) {
        k_edge<<<NB * NN, 512, 0, stream>>>(x, Ai, AjB,
            ew1 + ((size_t)l * 513 + 512) * HH, eb2 + l * HH,
            ew2P + (size_t)l * HH * HH, cw1P + (size_t)l * HH * HH,
            cb1 + l * HH, cw2 + l * HH, cb2 + l, magg, xdelta);
        int ln = (l + 1 < LL) ? (l + 1) : LL - 1;  // params unused when has_ln=0
        k_node_ln<<<NB * NN / 2, 256, 0, stream>>>(hn, magg,
            nw1 + (size_t)l * 2 * HH * HH, nb1 + l * HH,
            nw2 + (size_t)l * HH * HH, nb2 + l * HH, h, x, xdelta,
            ln_g + ln * HH, ln_b + ln * HH,
            ew1 + (size_t)ln * 513 * HH, eb1 + ln * HH,
            hn, Ai, AjB, (l + 1 < LL) ? 1 : 0);
    }

    k_decoder<<<NB * NN / 2, 256, 0, stream>>>(h, dec_w1, dec_b1, dec_w2, dec_b2,
                                               dec_w3, dec_b3, (float*)d_out);
}